// Round 1
// baseline (1136.441 us; speedup 1.0000x reference)
//
#include <hip/hip_runtime.h>

// Product VQ: B=64, T=2048, D=512, C=4, K=128, d=128.
// Outputs (concatenated in d_out, all read back as float32):
//   [0] quantized_sg : 64*2048*512 = 67108864 floats
//   [1] encoding_indices : 131072 values (written as float; harness casts ref int->f32)
//   [2] quantization_loss : 131072 floats
//
// Strategy: per (n,c) distance surrogate s_k = 0.5*|e_k|^2 - <x, e_k>  (argmin
// matches argmin of full distance). fp32 main pass with min/second-min tracking;
// rows whose gap < TAU get an exact fp64 re-evaluation -> true argmin fidelity.

#define NTOK 131072   // B*T
#define DF   512      // D
#define CS   4        // C
#define DS   128      // d
#define KC   128      // K
#define RPB  64       // rows per block
#define RPW  16       // rows per wave
#define RPI  8        // rows per register-blocked iteration
#define TAU  0.25f

// XOR swizzle: element (k,d) lives at elds[k*DS + ((d/4 ^ (k&7))*4) + d%4].
// Conflict-free b128 reads when 64 lanes read 64 consecutive k at the same d.
__device__ __forceinline__ int swz(int k, int d) {
  return k * DS + ((((d >> 2) ^ (k & 7))) << 2) + (d & 3);
}

__global__ __launch_bounds__(256, 2)
void pvq_main(const float* __restrict__ inp, const float* __restrict__ emb,
              float* __restrict__ outq, int* __restrict__ idx_ws,
              float* __restrict__ dist_ws) {
  __shared__ float elds[KC * DS];  // 64 KB, swizzled

  const int c    = blockIdx.y;
  const int t    = threadIdx.x;
  const int lane = t & 63;
  const int wid  = __builtin_amdgcn_readfirstlane(t >> 6);
  const int n0   = blockIdx.x * RPB + wid * RPW;

  // ---- stage embeddings[c] into LDS (swizzled), coalesced float4 ----
  {
    const float4* eg = (const float4*)(emb + (size_t)c * KC * DS);
    #pragma unroll
    for (int it = 0; it < (KC * DS / 4) / 256; ++it) {
      int i = it * 256 + t;           // float4 index, 0..4095
      float4 v = eg[i];
      int k  = i >> 5;                // (i*4)/128
      int c4 = i & 31;                // chunk within row
      *(float4*)&elds[k * DS + (((c4 ^ (k & 7))) << 2)] = v;
    }
  }
  __syncthreads();

  const int k1 = lane, k2 = lane + 64;

  // ---- per-lane 0.5*|e_k|^2 for the two owned codes ----
  float he1 = 0.f, he2 = 0.f;
  #pragma unroll 4
  for (int dd = 0; dd < DS; dd += 4) {
    float4 a = *(const float4*)&elds[k1 * DS + ((((dd >> 2) ^ (k1 & 7))) << 2)];
    float4 b = *(const float4*)&elds[k2 * DS + ((((dd >> 2) ^ (k2 & 7))) << 2)];
    he1 = fmaf(a.x, a.x, he1); he1 = fmaf(a.y, a.y, he1);
    he1 = fmaf(a.z, a.z, he1); he1 = fmaf(a.w, a.w, he1);
    he2 = fmaf(b.x, b.x, he2); he2 = fmaf(b.y, b.y, he2);
    he2 = fmaf(b.z, b.z, he2); he2 = fmaf(b.w, b.w, he2);
  }
  he1 *= 0.5f; he2 *= 0.5f;

  // ---- main loop: RPI rows at a time ----
  for (int g = 0; g < RPW; g += RPI) {
    const int nb = n0 + g;
    const float* xbase = inp + (size_t)nb * DF + c * DS;

    float acc1[RPI], acc2[RPI];
    #pragma unroll
    for (int r = 0; r < RPI; ++r) { acc1[r] = 0.f; acc2[r] = 0.f; }

    #pragma unroll 2
    for (int dd = 0; dd < DS; dd += 4) {
      float4 e1 = *(const float4*)&elds[k1 * DS + ((((dd >> 2) ^ (k1 & 7))) << 2)];
      float4 e2 = *(const float4*)&elds[k2 * DS + ((((dd >> 2) ^ (k2 & 7))) << 2)];
      #pragma unroll
      for (int r = 0; r < RPI; ++r) {
        float4 x = *(const float4*)(xbase + (size_t)r * DF + dd);  // wave-uniform
        acc1[r] = fmaf(x.x, e1.x, acc1[r]);
        acc1[r] = fmaf(x.y, e1.y, acc1[r]);
        acc1[r] = fmaf(x.z, e1.z, acc1[r]);
        acc1[r] = fmaf(x.w, e1.w, acc1[r]);
        acc2[r] = fmaf(x.x, e2.x, acc2[r]);
        acc2[r] = fmaf(x.y, e2.y, acc2[r]);
        acc2[r] = fmaf(x.z, e2.z, acc2[r]);
        acc2[r] = fmaf(x.w, e2.w, acc2[r]);
      }
    }

    #pragma unroll
    for (int r = 0; r < RPI; ++r) {
      const int n = nb + r;
      float sA = he1 - acc1[r];
      float sB = he2 - acc2[r];
      float s1, s2; int kb;
      if (sA <= sB) { s1 = sA; kb = k1; s2 = sB; }
      else          { s1 = sB; kb = k2; s2 = sA; }

      // butterfly: carry (min, argmin-with-lowest-k, second-min)
      #pragma unroll
      for (int off = 32; off > 0; off >>= 1) {
        float o1  = __shfl_xor(s1, off);
        int   okb = __shfl_xor(kb, off);
        float o2  = __shfl_xor(s2, off);
        float ns2 = fminf(fmaxf(s1, o1), fminf(s2, o2));
        if (o1 < s1 || (o1 == s1 && okb < kb)) { s1 = o1; kb = okb; }
        s2 = ns2;
      }

      // rare exact path: fp32 gap too small to trust -> fp64 re-evaluation
      if (s2 - s1 < TAU) {
        const float* xr = xbase + (size_t)r * DF;
        double dA = 0.0, dB = 0.0, qA = 0.0, qB = 0.0;
        for (int d = 0; d < DS; ++d) {
          double xv = (double)xr[d];
          double a  = (double)elds[swz(k1, d)];
          double b  = (double)elds[swz(k2, d)];
          dA += a * xv; qA += a * a;
          dB += b * xv; qB += b * b;
        }
        double sAd = 0.5 * qA - dA;
        double sBd = 0.5 * qB - dB;
        double s1d; int kd;
        if (sAd <= sBd) { s1d = sAd; kd = k1; }
        else            { s1d = sBd; kd = k2; }
        #pragma unroll
        for (int off = 32; off > 0; off >>= 1) {
          double o = __shfl_xor(s1d, off);
          int   ok = __shfl_xor(kd, off);
          if (o < s1d || (o == s1d && ok < kd)) { s1d = o; kd = ok; }
        }
        kb = kd;
      }
      kb = __builtin_amdgcn_readfirstlane(kb);

      // ---- epilogue: write quantized row-chunk, accumulate distortion ----
      const float* xr = xbase + (size_t)r * DF;
      const int d0 = 2 * lane;
      float q0 = elds[swz(kb, d0)];
      float q1 = elds[swz(kb, d0 + 1)];
      float2* qout = (float2*)(outq + (size_t)n * DF + c * DS);
      qout[lane] = make_float2(q0, q1);

      float x0 = xr[d0], x1 = xr[d0 + 1];
      float t0 = q0 - x0, t1 = q1 - x1;
      float p = fmaf(t0, t0, t1 * t1);
      #pragma unroll
      for (int off = 32; off > 0; off >>= 1) p += __shfl_xor(p, off);
      if (lane == 0) {
        idx_ws[n * CS + c]  = kb;
        dist_ws[n * CS + c] = p;
      }
    }
  }
}

__global__ void pvq_tail(const int* __restrict__ idx_ws,
                         const float* __restrict__ dist_ws,
                         float* __restrict__ out_enc,
                         float* __restrict__ out_loss) {
  int n = blockIdx.x * blockDim.x + threadIdx.x;
  if (n >= NTOK) return;
  int4   k  = *(const int4*)&idx_ws[(size_t)n * 4];
  float4 dv = *(const float4*)&dist_ws[(size_t)n * 4];
  int enc = ((k.x * KC + k.y) * KC + k.z) * KC + k.w;
  out_enc[n]  = (float)enc;
  out_loss[n] = 1.25f * (((dv.x + dv.y) + dv.z) + dv.w);
}

extern "C" void kernel_launch(void* const* d_in, const int* in_sizes, int n_in,
                              void* d_out, int out_size, void* d_ws, size_t ws_size,
                              hipStream_t stream) {
  const float* inp = (const float*)d_in[0];
  const float* emb = (const float*)d_in[1];

  float* outq     = (float*)d_out;
  float* out_enc  = outq + (size_t)NTOK * DF;   // 67108864
  float* out_loss = out_enc + NTOK;

  int*   idx_ws  = (int*)d_ws;                  // 524288 ints  (2 MB)
  float* dist_ws = (float*)d_ws + (size_t)NTOK * CS;  // 524288 floats (2 MB)

  dim3 grid(NTOK / RPB, CS);
  pvq_main<<<grid, 256, 0, stream>>>(inp, emb, outq, idx_ws, dist_ws);
  pvq_tail<<<(NTOK + 255) / 256, 256, 0, stream>>>(idx_ws, dist_ws, out_enc, out_loss);
}

// Round 2
// 671.441 us; speedup vs baseline: 1.6925x; 1.6925x over previous
//
#include <hip/hip_runtime.h>

// Product VQ: B=64, T=2048, D=512, C=4, K=128, d=128.
// Round 2: f16 MFMA distance pass (16x16x32), memory-bound streaming design.
//   - e[c] staged to LDS as f16 (pitch 136 halves -> 2-way-max bank aliasing)
//   - x loaded lane-parallel in A-frag layout (row = lane&15, k = quad*8+j)
//   - distances s_k = 0.5|e_k|^2 - <x,e_k>, e2 exact fp32
//   - per-row top-2 (s1,k1,s2,k2) tracked; gap < TAU -> fp64 exact re-eval
//   - quantized gathered as fp32 from global e (L2-hot), loss = |x|^2 + 2*s_min

#define NTOK 131072
#define DF   512
#define CS   4
#define DS   128
#define KC   128
#define PITCH 136   // f16 units per LDS code row (128 + 8 pad)
#define TAU  0.5f

typedef _Float16 half8 __attribute__((ext_vector_type(8)));
typedef float   f32x4 __attribute__((ext_vector_type(4)));

__global__ __launch_bounds__(256, 4)
void pvq_main(const float* __restrict__ inp, const float* __restrict__ emb,
              float* __restrict__ outq, int* __restrict__ idx_ws,
              float* __restrict__ dist_ws) {
  __shared__ _Float16 elds[KC * PITCH];  // 34 KB
  __shared__ float    e2s[KC];

  const int c    = blockIdx.y;
  const int t    = threadIdx.x;
  const int lane = t & 63;
  const int wid  = t >> 6;
  const int nf   = lane & 15;   // code index within 16-tile / A row index
  const int quad = lane >> 4;

  const float* ebase = emb + (size_t)c * KC * DS;

  // ---- stage e -> f16 LDS (coalesced float4) ----
  {
    const float4* eg = (const float4*)ebase;
    #pragma unroll
    for (int it = 0; it < 16; ++it) {
      int i = it * 256 + t;            // 0..4095
      float4 v = eg[i];
      int code = i >> 5;               // 32 float4 per code row
      int dpos = (i & 31) << 2;
      _Float16* p = &elds[code * PITCH + dpos];
      p[0] = (_Float16)v.x; p[1] = (_Float16)v.y;
      p[2] = (_Float16)v.z; p[3] = (_Float16)v.w;
    }
    // exact fp32 0.5*|e_k|^2, one thread per code (reads global, L2-hot)
    if (t < KC) {
      const float4* er = (const float4*)(ebase + (size_t)t * DS);
      float s = 0.f;
      #pragma unroll 8
      for (int i = 0; i < 32; ++i) {
        float4 v = er[i];
        s = fmaf(v.x, v.x, s); s = fmaf(v.y, v.y, s);
        s = fmaf(v.z, v.z, s); s = fmaf(v.w, v.w, s);
      }
      e2s[t] = 0.5f * s;
    }
  }
  __syncthreads();

  float e2r[8];
  #pragma unroll
  for (int nt = 0; nt < 8; ++nt) e2r[nt] = e2s[nt * 16 + nf];

  // ---- 4 row-tiles (16 rows each) per wave ----
  const int rowblk = blockIdx.x * 256 + wid * 64;
  for (int tile = 0; tile < 4; ++tile) {
    const int n0 = rowblk + tile * 16;
    const float* xrow = inp + (size_t)(n0 + nf) * DF + c * DS;

    // A-frags (row = nf, depth chunk = quad*8 + j + 32*kc) + |x_row|^2 partial
    half8 afrag[4];
    float x2 = 0.f;
    #pragma unroll
    for (int kc4 = 0; kc4 < 4; ++kc4) {
      const float4* xp = (const float4*)(xrow + kc4 * 32 + quad * 8);
      float4 v0 = xp[0], v1 = xp[1];
      x2 = fmaf(v0.x, v0.x, x2); x2 = fmaf(v0.y, v0.y, x2);
      x2 = fmaf(v0.z, v0.z, x2); x2 = fmaf(v0.w, v0.w, x2);
      x2 = fmaf(v1.x, v1.x, x2); x2 = fmaf(v1.y, v1.y, x2);
      x2 = fmaf(v1.z, v1.z, x2); x2 = fmaf(v1.w, v1.w, x2);
      afrag[kc4][0] = (_Float16)v0.x; afrag[kc4][1] = (_Float16)v0.y;
      afrag[kc4][2] = (_Float16)v0.z; afrag[kc4][3] = (_Float16)v0.w;
      afrag[kc4][4] = (_Float16)v1.x; afrag[kc4][5] = (_Float16)v1.y;
      afrag[kc4][6] = (_Float16)v1.z; afrag[kc4][7] = (_Float16)v1.w;
    }
    // full |x_row|^2 to every lane holding that row (reduce across quads)
    x2 += __shfl_xor(x2, 16);
    x2 += __shfl_xor(x2, 32);

    // ---- 32 MFMAs: D[row 16][code 128] ----
    f32x4 acc[8];
    #pragma unroll
    for (int nt = 0; nt < 8; ++nt) acc[nt] = (f32x4){0.f, 0.f, 0.f, 0.f};
    #pragma unroll
    for (int nt = 0; nt < 8; ++nt) {
      #pragma unroll
      for (int kc4 = 0; kc4 < 4; ++kc4) {
        half8 b = *(const half8*)&elds[(nt * 16 + nf) * PITCH + kc4 * 32 + quad * 8];
        acc[nt] = __builtin_amdgcn_mfma_f32_16x16x32_f16(afrag[kc4], b, acc[nt], 0, 0, 0);
      }
    }

    // ---- per-lane top-2 over the 8 code-tiles (C layout: col=nf, row=quad*4+reg)
    float s1[4], s2[4]; int k1[4], k2[4];
    #pragma unroll
    for (int r = 0; r < 4; ++r) { s1[r] = 1e30f; s2[r] = 1e30f; k1[r] = 0; k2[r] = 0; }
    #pragma unroll
    for (int nt = 0; nt < 8; ++nt) {
      int kidx = nt * 16 + nf;
      #pragma unroll
      for (int r = 0; r < 4; ++r) {
        float s = e2r[nt] - acc[nt][r];
        if (s < s1[r])      { s2[r] = s1[r]; k2[r] = k1[r]; s1[r] = s; k1[r] = kidx; }
        else if (s < s2[r]) { s2[r] = s;     k2[r] = kidx; }
      }
    }
    // ---- merge across the 16 lanes of each quad-group ----
    #pragma unroll
    for (int off = 1; off < 16; off <<= 1) {
      #pragma unroll
      for (int r = 0; r < 4; ++r) {
        float o1 = __shfl_xor(s1[r], off); int ok1 = __shfl_xor(k1[r], off);
        float o2 = __shfl_xor(s2[r], off); int ok2 = __shfl_xor(k2[r], off);
        bool takeo = (o1 < s1[r]) || (o1 == s1[r] && ok1 < k1[r]);
        float w1 = takeo ? o1 : s1[r]; int wk1 = takeo ? ok1 : k1[r];
        float l1 = takeo ? s1[r] : o1; int lk1 = takeo ? k1[r] : ok1;
        float n2 = l1; int nk2 = lk1;
        if (s2[r] < n2) { n2 = s2[r]; nk2 = k2[r]; }
        if (o2 < n2)    { n2 = o2;    nk2 = ok2;  }
        s1[r] = w1; k1[r] = wk1; s2[r] = n2; k2[r] = nk2;
      }
    }

    // ---- epilogue: 16 rows ----
    #pragma unroll 1
    for (int r = 0; r < 16; ++r) {
      const int srcl = (r >> 2) * 16;
      float s1r = __shfl(s1[r & 3], srcl);
      int   kb  = __shfl(k1[r & 3], srcl);
      float s2r = __shfl(s2[r & 3], srcl);
      int   kb2 = __shfl(k2[r & 3], srcl);
      float x2r = __shfl(x2, r);
      const int n = n0 + r;
      float p;
      if (s2r - s1r < TAU) {
        // exact fp64 re-eval of both candidates, whole wave cooperates
        const float2* xp = (const float2*)(inp + (size_t)n * DF + c * DS);
        const float2* eA = (const float2*)(ebase + (size_t)kb  * DS);
        const float2* eB = (const float2*)(ebase + (size_t)kb2 * DS);
        float2 xv = xp[lane], a = eA[lane], b = eB[lane];
        double pA = (double)(xv.x - a.x) * (xv.x - a.x) + (double)(xv.y - a.y) * (xv.y - a.y);
        double pB = (double)(xv.x - b.x) * (xv.x - b.x) + (double)(xv.y - b.y) * (xv.y - b.y);
        #pragma unroll
        for (int off = 1; off < 64; off <<= 1) {
          pA += __shfl_xor(pA, off);
          pB += __shfl_xor(pB, off);
        }
        if (pB < pA || (pB == pA && kb2 < kb)) { kb = kb2; p = (float)pB; }
        else                                   { p = (float)pA; }
      } else {
        p = x2r + 2.f * s1r;
      }
      // gather exact fp32 code row (L2-hot) and write quantized
      const float2* ef = (const float2*)(ebase + (size_t)kb * DS);
      float2 q = ef[lane];
      *(float2*)(outq + (size_t)n * DF + c * DS + 2 * lane) = q;
      if (lane == r) { idx_ws[n * CS + c] = kb; dist_ws[n * CS + c] = p; }
    }
  }
}

__global__ void pvq_tail(const int* __restrict__ idx_ws,
                         const float* __restrict__ dist_ws,
                         float* __restrict__ out_enc,
                         float* __restrict__ out_loss) {
  int n = blockIdx.x * blockDim.x + threadIdx.x;
  if (n >= NTOK) return;
  int4   k  = *(const int4*)&idx_ws[(size_t)n * 4];
  float4 dv = *(const float4*)&dist_ws[(size_t)n * 4];
  int enc = ((k.x * KC + k.y) * KC + k.z) * KC + k.w;
  out_enc[n]  = (float)enc;
  out_loss[n] = 1.25f * (((dv.x + dv.y) + dv.z) + dv.w);
}

extern "C" void kernel_launch(void* const* d_in, const int* in_sizes, int n_in,
                              void* d_out, int out_size, void* d_ws, size_t ws_size,
                              hipStream_t stream) {
  const float* inp = (const float*)d_in[0];
  const float* emb = (const float*)d_in[1];

  float* outq     = (float*)d_out;
  float* out_enc  = outq + (size_t)NTOK * DF;
  float* out_loss = out_enc + NTOK;

  int*   idx_ws  = (int*)d_ws;
  float* dist_ws = (float*)d_ws + (size_t)NTOK * CS;

  dim3 grid(NTOK / 256, CS);   // 512 x 4
  pvq_main<<<grid, 256, 0, stream>>>(inp, emb, outq, idx_ws, dist_ws);
  pvq_tail<<<(NTOK + 255) / 256, 256, 0, stream>>>(idx_ws, dist_ws, out_enc, out_loss);
}